// Round 2
// baseline (315.558 us; speedup 1.0000x reference)
//
#include <hip/hip_runtime.h>

namespace {
constexpr int kBB = 64, kH = 64, kW = 64, kC = 128, kP = 64;
constexpr int kHW = kH * kW;                 // 4096
constexpr long kRows = (long)kBB * kHW;      // 262144
constexpr long kOutElems = kRows * kC;       // 33554432

typedef float f4 __attribute__((ext_vector_type(4)));  // native vec for nontemporal builtins

// Fused: per 64-row block
//   (a) out[row][c] = sum_p s[row][p] * k[p][c]   (register-tiled vector GEMM,
//       k read through L1/L2 — it is 32 KB and cache-resident; LDS kept small
//       (20.6 KB) so ~6 blocks/CU are resident vs 2-3 before)
//   (b) partial zsum[b][c] += sum_rows z[row][c], z2[b] += sum z^2 (atomics,
//       deferred to after the GEMM so atomic latency is off the critical path)
__global__ __launch_bounds__(256, 6) void fused_kernel(const float* __restrict__ z,
                                                       const float* __restrict__ s,
                                                       const float* __restrict__ kmat,
                                                       float* __restrict__ out,
                                                       float* __restrict__ zsum,
                                                       float* __restrict__ z2) {
  __shared__ f4 s_lds[64][kP / 4];   // 16 KB
  __shared__ f4 red[8][32];          // 4 KB (z column partials)
  __shared__ float qred[4];

  const int t = threadIdx.x;
  const int cq = t & 31;   // float4-column 0..31
  const int tg = t >> 5;   // row-group 0..7
  const long rowbase = (long)blockIdx.x * 64;
  const int b = (int)(rowbase >> 12);    // 4096 rows per batch image

  // ---- stage s tile (contiguous 16 KB, streamed once -> nontemporal) ----
  const f4* s4 = reinterpret_cast<const f4*>(s + rowbase * kP);
  f4* s_flat = &s_lds[0][0];
#pragma unroll
  for (int i = 0; i < 4; ++i)
    s_flat[t + 256 * i] = __builtin_nontemporal_load(&s4[t + 256 * i]);

  // ---- stream this block's 64 z rows (read-once -> nontemporal) ----
  const f4* z4 = reinterpret_cast<const f4*>(z + rowbase * kC);
  float sx = 0.f, sy = 0.f, sz = 0.f, sw = 0.f, q = 0.f;
#pragma unroll
  for (int j = 0; j < 8; ++j) {
    const f4 v = __builtin_nontemporal_load(&z4[(tg + 8 * j) * 32 + cq]);
    sx += v.x; sy += v.y; sz += v.z; sw += v.w;
    q += v.x * v.x + v.y * v.y + v.z * v.z + v.w * v.w;
  }
  red[tg][cq] = (f4){sx, sy, sz, sw};
  for (int off = 32; off > 0; off >>= 1) q += __shfl_down(q, off, 64);
  if ((t & 63) == 0) qred[t >> 6] = q;

  __syncthreads();  // covers s staging + red/qred

  // ---- GEMM: each thread 8 rows x 1 float4 of c; k from L1/L2 ----
  const f4* k4 = reinterpret_cast<const f4*>(kmat);  // k4[p*32 + cq]
  f4 acc[8];
#pragma unroll
  for (int j = 0; j < 8; ++j) acc[j] = (f4){0.f, 0.f, 0.f, 0.f};

#pragma unroll 2
  for (int pc = 0; pc < 16; ++pc) {  // p in chunks of 4
    const f4 k0 = k4[(4 * pc + 0) * 32 + cq];
    const f4 k1 = k4[(4 * pc + 1) * 32 + cq];
    const f4 k2 = k4[(4 * pc + 2) * 32 + cq];
    const f4 k3 = k4[(4 * pc + 3) * 32 + cq];
#pragma unroll
    for (int j = 0; j < 8; ++j) {
      const f4 sv = s_lds[tg + 8 * j][pc];  // LDS broadcast across 32 lanes
      acc[j].x += sv.x * k0.x + sv.y * k1.x + sv.z * k2.x + sv.w * k3.x;
      acc[j].y += sv.x * k0.y + sv.y * k1.y + sv.z * k2.y + sv.w * k3.y;
      acc[j].z += sv.x * k0.z + sv.y * k1.z + sv.z * k2.z + sv.w * k3.z;
      acc[j].w += sv.x * k0.w + sv.y * k1.w + sv.z * k2.w + sv.w * k3.w;
    }
  }

  f4* out4 = reinterpret_cast<f4*>(out + rowbase * kC);
#pragma unroll
  for (int j = 0; j < 8; ++j)
    __builtin_nontemporal_store(acc[j], &out4[(tg + 8 * j) * 32 + cq]);

  // ---- finish z reduction AFTER the GEMM: 32 lanes fold 8 row-groups ----
  if (tg == 0) {
    f4 tot = red[0][cq];
#pragma unroll
    for (int j = 1; j < 8; ++j) {
      const f4 v = red[j][cq];
      tot.x += v.x; tot.y += v.y; tot.z += v.z; tot.w += v.w;
    }
    atomicAdd(&zsum[b * kC + cq * 4 + 0], tot.x);
    atomicAdd(&zsum[b * kC + cq * 4 + 1], tot.y);
    atomicAdd(&zsum[b * kC + cq * 4 + 2], tot.z);
    atomicAdd(&zsum[b * kC + cq * 4 + 3], tot.w);
    if (cq == 0) atomicAdd(&z2[b], qred[0] + qred[1] + qred[2] + qred[3]);
  }
}

// distance[b][p] = z2[b] - 2*dot(zsum[b],k[p]) + 4096*||k[p]||^2
__global__ __launch_bounds__(256) void dist_kernel(const float* __restrict__ zsum,
                                                   const float* __restrict__ z2,
                                                   const float* __restrict__ kmat,
                                                   float* __restrict__ dist) {
  const int g = blockIdx.x * 256 + threadIdx.x;  // 0..4095
  const int b = g >> 6;
  const int p = g & 63;
  const f4* zs4 = reinterpret_cast<const f4*>(zsum + b * kC);
  const f4* k4 = reinterpret_cast<const f4*>(kmat + p * kC);
  float dot = 0.f, k2 = 0.f;
#pragma unroll 8
  for (int i = 0; i < kC / 4; ++i) {
    const f4 kk = k4[i];
    const f4 zz = zs4[i];
    dot += zz.x * kk.x + zz.y * kk.y + zz.z * kk.z + zz.w * kk.w;
    k2 += kk.x * kk.x + kk.y * kk.y + kk.z * kk.z + kk.w * kk.w;
  }
  dist[g] = z2[b] - 2.f * dot + (float)kHW * k2;
}

}  // namespace

extern "C" void kernel_launch(void* const* d_in, const int* in_sizes, int n_in,
                              void* d_out, int out_size, void* d_ws, size_t ws_size,
                              hipStream_t stream) {
  const float* z = (const float*)d_in[0];      // (64,64,64,128)
  const float* s = (const float*)d_in[1];      // (64,64,64,64)
  const float* kmat = (const float*)d_in[2];   // (64,1,1,128)

  float* out = (float*)d_out;                  // 33554432 floats
  float* dist = out + kOutElems;               // 4096 floats

  float* zsum = (float*)d_ws;                  // 64*128 floats
  float* z2 = zsum + kBB * kC;                 // 64 floats

  // zero the atomic accumulators (ws is poisoned 0xAA each call)
  (void)hipMemsetAsync(d_ws, 0, (size_t)(kBB * kC + kBB) * sizeof(float), stream);

  fused_kernel<<<(int)(kRows / 64), 256, 0, stream>>>(z, s, kmat, out, zsum, z2);
  dist_kernel<<<16, 256, 0, stream>>>(zsum, z2, kmat, dist);
}